// Round 1
// baseline (243.232 us; speedup 1.0000x reference)
//
#include <hip/hip_runtime.h>
#include <math.h>

// DirectionalContrastiveLoss — N=8, C=192, H=W=112, T=0.1
//
// loss = mean_{n,m,i,j} [ log(denom+1e-6) - log(exp(l)*mask) ]
//   l[n,m,i,j]  = dot(fn[n,:,i,j], fn[n,:,i+d0[m,i,j], j+d1[m,i,j]]) * 10
//   denom[n,i,j]= sum_m exp(l)*mask,  mask = (labels[m,i,j]==labels[n,ni,nj])
//   fn = features / max(||features||_c, 1e-12)
//
// Single fused pass over features: per channel, stage a 6x114 halo tile into
// LDS (double-buffered, one barrier per channel), accumulate the 9 neighbor
// dot products in registers and per-slot sum-of-squares in LDS (gives the
// norms for free, including halo pixels). Normalize + softmax + log in the
// epilogue; block-reduce; double atomicAdd into d_ws; finalize kernel writes
// the mean.

namespace {
constexpr int N_ = 8, C_ = 192, H_ = 112, W_ = 112;
constexpr int HW = H_ * W_;
constexpr int TH = 4;                 // pixel rows per block
constexpr int TROWS = TH + 2;         // 6 rows incl. halo
constexpr int TWID = W_ + 2;          // 114 cols incl. halo
constexpr int TILE_E = TROWS * TWID;  // 684
constexpr int NTHREADS = TH * W_;     // 448 = 7 waves
constexpr float INV_T = 10.0f;
constexpr double TOTAL = (double)N_ * N_ * H_ * W_;  // 802816
}

__device__ __forceinline__ float sel3(int d, float a, float b, float c) {
    // d<0 -> a, d==0 -> b, d>0 -> c
    float r = (d < 0) ? a : b;
    return (d > 0) ? c : r;
}

extern "C" __global__ void __launch_bounds__(NTHREADS)
dcl_main(const float* __restrict__ feat,
         const int* __restrict__ labels,
         const int* __restrict__ dirs,
         double* __restrict__ acc)
{
    __shared__ float tileA[TILE_E];
    __shared__ float tileB[TILE_E];
    __shared__ float ssbuf[TILE_E];
    __shared__ float red[8];

    const int tid = threadIdx.x;
    const int n   = blockIdx.y;
    const int gy0 = blockIdx.x * TH;

    // ---- staging assignment: thread stages slot tid, and tid+448 if < 684
    int gofs0, gofs1 = -1;
    {
        int t = tid;
        int r = t / TWID, col = t - r * TWID;
        int giq = min(max(gy0 + r - 1, 0), H_ - 1);
        int gjq = min(max(col - 1, 0), W_ - 1);
        gofs0 = giq * W_ + gjq;
        ssbuf[t] = 0.0f;
        t = tid + NTHREADS;
        if (t < TILE_E) {
            r = t / TWID; col = t - r * TWID;
            giq = min(max(gy0 + r - 1, 0), H_ - 1);
            gjq = min(max(col - 1, 0), W_ - 1);
            gofs1 = giq * W_ + gjq;
            ssbuf[t] = 0.0f;
        }
    }

    const int ty = tid / W_;          // 0..3
    const int tx = tid - ty * W_;     // 0..111
    const int gi = gy0 + ty;
    const int gj = tx;
    const int ci = (ty + 1) * TWID + (tx + 1);

    const float* plane = feat + (size_t)n * C_ * HW;

    float s00=0.f, s01=0.f, s02=0.f;
    float s10=0.f, s11=0.f, s12=0.f;
    float s20=0.f, s21=0.f, s22=0.f;

    // ---- prologue: stage channel 0 into tileA
    {
        float v = plane[gofs0];
        tileA[tid] = v; ssbuf[tid] += v * v;
        if (gofs1 >= 0) {
            float v1 = plane[gofs1];
            tileA[tid + NTHREADS] = v1; ssbuf[tid + NTHREADS] += v1 * v1;
        }
    }
    __syncthreads();

    // ---- channel loop: 1 barrier per channel (double-buffered tile)
    for (int c = 0; c < C_; ++c) {
        const float* cur = (c & 1) ? tileB : tileA;
        float*       nxt = (c & 1) ? tileA : tileB;
        if (c + 1 < C_) {
            const float* p = plane + (size_t)(c + 1) * HW;
            float v = p[gofs0];
            nxt[tid] = v; ssbuf[tid] += v * v;
            if (gofs1 >= 0) {
                float v1 = p[gofs1];
                nxt[tid + NTHREADS] = v1; ssbuf[tid + NTHREADS] += v1 * v1;
            }
        }
        float fc = cur[ci];
        s00 += fc * cur[ci - TWID - 1];
        s01 += fc * cur[ci - TWID];
        s02 += fc * cur[ci - TWID + 1];
        s10 += fc * cur[ci - 1];
        s11 += fc * fc;
        s12 += fc * cur[ci + 1];
        s20 += fc * cur[ci + TWID - 1];
        s21 += fc * cur[ci + TWID];
        s22 += fc * cur[ci + TWID + 1];
        __syncthreads();
    }

    // ---- ssbuf -> inverse norms, in place (same thread owns same slots)
    {
        float v = ssbuf[tid];
        ssbuf[tid] = 1.0f / fmaxf(sqrtf(v), 1e-12f);
        if (tid + NTHREADS < TILE_E) {
            float v1 = ssbuf[tid + NTHREADS];
            ssbuf[tid + NTHREADS] = 1.0f / fmaxf(sqrtf(v1), 1e-12f);
        }
    }
    __syncthreads();

    // ---- normalized logits for the 9 neighbor offsets
    const float invc = ssbuf[ci] * INV_T;
    const float l00 = s00 * invc * ssbuf[ci - TWID - 1];
    const float l01 = s01 * invc * ssbuf[ci - TWID];
    const float l02 = s02 * invc * ssbuf[ci - TWID + 1];
    const float l10 = s10 * invc * ssbuf[ci - 1];
    const float l11 = s11 * invc * ssbuf[ci];
    const float l12 = s12 * invc * ssbuf[ci + 1];
    const float l20 = s20 * invc * ssbuf[ci + TWID - 1];
    const float l21 = s21 * invc * ssbuf[ci + TWID];
    const float l22 = s22 * invc * ssbuf[ci + TWID + 1];

    // ---- per-m softmax terms
    const int pix = gi * W_ + gj;
    float denom = 0.0f;
    float sumlog = 0.0f;   // sum_m log(exp(l_m)*mask_m)
    const int myLab = 0;   // placeholder; real read below
    (void)myLab;
#pragma unroll
    for (int m = 0; m < N_; ++m) {
        int d0 = dirs[((m * 2 + 0) * H_ + gi) * W_ + gj];
        int d1 = dirs[((m * 2 + 1) * H_ + gi) * W_ + gj];
        float r0 = sel3(d1, l00, l01, l02);
        float r1 = sel3(d1, l10, l11, l12);
        float r2 = sel3(d1, l20, l21, l22);
        float lm = sel3(d0, r0, r1, r2);
        int labm = labels[m * HW + pix];
        int labn = labels[n * HW + (gi + d0) * W_ + (gj + d1)];
        bool mask = (labm == labn);
        float e = mask ? __expf(lm) : 0.0f;
        denom += e;
        sumlog += mask ? lm : -INFINITY;
    }
    float logd = __logf(denom + 1e-6f);
    float lp = 8.0f * logd - sumlog;   // sum over m of (logd - log(e_m))

    // ---- block reduction (7 waves)
    #pragma unroll
    for (int off = 32; off > 0; off >>= 1)
        lp += __shfl_down(lp, off, 64);
    const int wave = tid >> 6, lane = tid & 63;
    if (lane == 0) red[wave] = lp;
    __syncthreads();
    if (tid == 0) {
        float s = 0.0f;
        #pragma unroll
        for (int w = 0; w < NTHREADS / 64; ++w) s += red[w];
        atomicAdd(acc, (double)s);
    }
}

extern "C" __global__ void dcl_final(const double* __restrict__ acc,
                                     float* __restrict__ out)
{
    out[0] = (float)(acc[0] / TOTAL);
}

extern "C" void kernel_launch(void* const* d_in, const int* in_sizes, int n_in,
                              void* d_out, int out_size, void* d_ws, size_t ws_size,
                              hipStream_t stream) {
    const float* feat   = (const float*)d_in[0];
    const int*   labels = (const int*)d_in[1];
    const int*   dirs   = (const int*)d_in[2];
    double* acc = (double*)d_ws;
    float*  out = (float*)d_out;

    hipMemsetAsync(acc, 0, sizeof(double), stream);
    dim3 grid(H_ / TH, N_);           // (28, 8)
    dcl_main<<<grid, NTHREADS, 0, stream>>>(feat, labels, dirs, acc);
    dcl_final<<<1, 1, 0, stream>>>(acc, out);
}

// Round 2
// 144.318 us; speedup vs baseline: 1.6854x; 1.6854x over previous
//
#include <hip/hip_runtime.h>
#include <math.h>

// DirectionalContrastiveLoss — N=8, C=192, H=W=112, T=0.1
//
// R2: chunked double-buffered channel loop (K=4 channels per barrier,
// prefetch loads for chunk t+1 issued before chunk t's compute => ~1100cyc
// of LDS work hides ~900cyc HBM latency), sum-of-squares accumulated in
// registers instead of LDS RMW. Barriers 193 -> 49.

namespace {
constexpr int N_ = 8, C_ = 192, H_ = 112, W_ = 112;
constexpr int HW = H_ * W_;
constexpr int TH = 4;                 // pixel rows per block
constexpr int TROWS = TH + 2;         // 6 rows incl. halo
constexpr int TWID = W_ + 2;          // 114 cols incl. halo
constexpr int TILE_E = TROWS * TWID;  // 684
constexpr int NT = TH * W_;           // 448 threads = 7 waves
constexpr int EXTRA = TILE_E - NT;    // 236 threads carry a 2nd slot
constexpr int K_ = 4;                 // channels per chunk
constexpr int NCHUNK = C_ / K_;       // 48
constexpr float INV_T = 10.0f;
constexpr double TOTAL = (double)N_ * N_ * H_ * W_;  // 802816
}

__device__ __forceinline__ float sel3(int d, float a, float b, float c) {
    float r = (d < 0) ? a : b;
    return (d > 0) ? c : r;
}

extern "C" __global__ void __launch_bounds__(NT)
dcl_main(const float* __restrict__ feat,
         const int* __restrict__ labels,
         const int* __restrict__ dirs,
         double* __restrict__ acc)
{
    __shared__ float tiles[2][K_][TILE_E];   // 21.9 KB
    __shared__ float ssbuf[TILE_E];
    __shared__ float red[8];

    const int tid = threadIdx.x;
    const int n   = blockIdx.y;
    const int gy0 = blockIdx.x * TH;

    // ---- staging slot -> clamped global offset
    int gofs0, gofs1 = 0;
    {
        int r = tid / TWID, col = tid - r * TWID;
        gofs0 = min(max(gy0 + r - 1, 0), H_ - 1) * W_ + min(max(col - 1, 0), W_ - 1);
        if (tid < EXTRA) {
            int t2 = tid + NT;
            r = t2 / TWID; col = t2 - r * TWID;
            gofs1 = min(max(gy0 + r - 1, 0), H_ - 1) * W_ + min(max(col - 1, 0), W_ - 1);
        }
    }

    const int ty = tid / W_;          // 0..3
    const int tx = tid - ty * W_;     // 0..111
    const int gi = gy0 + ty;
    const int gj = tx;
    const int ci = (ty + 1) * TWID + (tx + 1);

    const float* plane = feat + (size_t)n * C_ * HW;

    float ss0 = 0.0f, ss1 = 0.0f;     // register sum-of-squares per owned slot

    // ---- prologue: stage chunk 0 into buffer 0
    #pragma unroll
    for (int k = 0; k < K_; ++k) {
        float v = plane[(size_t)k * HW + gofs0];
        tiles[0][k][tid] = v; ss0 += v * v;
    }
    if (tid < EXTRA) {
        #pragma unroll
        for (int k = 0; k < K_; ++k) {
            float v = plane[(size_t)k * HW + gofs1];
            tiles[0][k][tid + NT] = v; ss1 += v * v;
        }
    }
    __syncthreads();

    float s00=0.f, s01=0.f, s02=0.f;
    float s10=0.f, s11=0.f, s12=0.f;
    float s20=0.f, s21=0.f, s22=0.f;

    // ---- chunk loop: 1 barrier per 4 channels, double-buffered
    for (int t = 0; t < NCHUNK; ++t) {
        float pv0[K_], pv1[K_];
        const bool more = (t + 1 < NCHUNK);
        if (more) {
            // issue prefetch loads FIRST — ~1100 cyc of compute below hides them
            const float* p = plane + (size_t)(t + 1) * K_ * HW;
            #pragma unroll
            for (int k = 0; k < K_; ++k) pv0[k] = p[(size_t)k * HW + gofs0];
            if (tid < EXTRA) {
                #pragma unroll
                for (int k = 0; k < K_; ++k) pv1[k] = p[(size_t)k * HW + gofs1];
            }
        }

        const float* cur = &tiles[t & 1][0][0];
        #pragma unroll
        for (int k = 0; k < K_; ++k) {
            const float* cp = cur + k * TILE_E;
            float fc = cp[ci];
            s00 += fc * cp[ci - TWID - 1];
            s01 += fc * cp[ci - TWID];
            s02 += fc * cp[ci - TWID + 1];
            s10 += fc * cp[ci - 1];
            s11 += fc * fc;
            s12 += fc * cp[ci + 1];
            s20 += fc * cp[ci + TWID - 1];
            s21 += fc * cp[ci + TWID];
            s22 += fc * cp[ci + TWID + 1];
        }

        if (more) {
            float* nxt = &tiles[(t + 1) & 1][0][0];
            #pragma unroll
            for (int k = 0; k < K_; ++k) {
                float v = pv0[k];
                nxt[k * TILE_E + tid] = v; ss0 += v * v;
            }
            if (tid < EXTRA) {
                #pragma unroll
                for (int k = 0; k < K_; ++k) {
                    float v = pv1[k];
                    nxt[k * TILE_E + tid + NT] = v; ss1 += v * v;
                }
            }
        }
        __syncthreads();
    }

    // ---- publish inverse norms (same thread owns same slots all along)
    ssbuf[tid] = 1.0f / fmaxf(sqrtf(ss0), 1e-12f);
    if (tid < EXTRA)
        ssbuf[tid + NT] = 1.0f / fmaxf(sqrtf(ss1), 1e-12f);
    __syncthreads();

    // ---- normalized logits for the 9 neighbor offsets
    const float invc = ssbuf[ci] * INV_T;
    const float l00 = s00 * invc * ssbuf[ci - TWID - 1];
    const float l01 = s01 * invc * ssbuf[ci - TWID];
    const float l02 = s02 * invc * ssbuf[ci - TWID + 1];
    const float l10 = s10 * invc * ssbuf[ci - 1];
    const float l11 = s11 * invc * ssbuf[ci];
    const float l12 = s12 * invc * ssbuf[ci + 1];
    const float l20 = s20 * invc * ssbuf[ci + TWID - 1];
    const float l21 = s21 * invc * ssbuf[ci + TWID];
    const float l22 = s22 * invc * ssbuf[ci + TWID + 1];

    // ---- per-m softmax terms
    const int pix = gi * W_ + gj;
    float denom = 0.0f;
    float sumlog = 0.0f;
    #pragma unroll
    for (int m = 0; m < N_; ++m) {
        int d0 = dirs[((m * 2 + 0) * H_ + gi) * W_ + gj];
        int d1 = dirs[((m * 2 + 1) * H_ + gi) * W_ + gj];
        float r0 = sel3(d1, l00, l01, l02);
        float r1 = sel3(d1, l10, l11, l12);
        float r2 = sel3(d1, l20, l21, l22);
        float lm = sel3(d0, r0, r1, r2);
        int labm = labels[m * HW + pix];
        int labn = labels[n * HW + (gi + d0) * W_ + (gj + d1)];
        bool mask = (labm == labn);
        float e = mask ? __expf(lm) : 0.0f;
        denom += e;
        sumlog += mask ? lm : -INFINITY;
    }
    float logd = __logf(denom + 1e-6f);
    float lp = 8.0f * logd - sumlog;

    // ---- block reduction (7 waves)
    #pragma unroll
    for (int off = 32; off > 0; off >>= 1)
        lp += __shfl_down(lp, off, 64);
    const int wave = tid >> 6, lane = tid & 63;
    if (lane == 0) red[wave] = lp;
    __syncthreads();
    if (tid == 0) {
        float s = 0.0f;
        #pragma unroll
        for (int w = 0; w < NT / 64; ++w) s += red[w];
        atomicAdd(acc, (double)s);
    }
}

extern "C" __global__ void dcl_final(const double* __restrict__ acc,
                                     float* __restrict__ out)
{
    out[0] = (float)(acc[0] / TOTAL);
}

extern "C" void kernel_launch(void* const* d_in, const int* in_sizes, int n_in,
                              void* d_out, int out_size, void* d_ws, size_t ws_size,
                              hipStream_t stream) {
    const float* feat   = (const float*)d_in[0];
    const int*   labels = (const int*)d_in[1];
    const int*   dirs   = (const int*)d_in[2];
    double* acc = (double*)d_ws;
    float*  out = (float*)d_out;

    hipMemsetAsync(acc, 0, sizeof(double), stream);
    dim3 grid(H_ / TH, N_);           // (28, 8) = 224 blocks
    dcl_main<<<grid, NT, 0, stream>>>(feat, labels, dirs, acc);
    dcl_final<<<1, 1, 0, stream>>>(acc, out);
}